// Round 12
// baseline (143.843 us; speedup 1.0000x reference)
//
#include <hip/hip_runtime.h>
#include <hip/hip_bf16.h>

// Round 12 (= r11 resubmitted; r11 was an infra timeout, never ran).
// r10 structure + LDS-atomic contention splitting.
//
// Algebra (unchanged): voxel = c>>1, u = c&1:
//   norm_center = mu = sum(u)/count, variance = mu*(1-mu),
//   density = count / glob[batch].  Per segment need only packed
//   (count, sum_ux, sum_uy, sum_uz) in one u32.
//
// Ledger: LDS-sort + coalesced copy-out is the proven write path (direct
// scatter amplifies HBM writes 3.5x, r9). Global cursor atomics are not
// the bottleneck (r8/r9). r10 (LDS raw cache + shfl scan) = 142.2 us.
// This round: split histogram+cursors into two wave-group halves (halves
// same-address LDS atomic serialization in phases A and C), uint4 phase-D
// LDS reads, single-wave shfl reduce for glob in stats.

#define BLOCK1 1024          // partition threads/block
#define PPT 8                // points per thread
#define PTS (BLOCK1 * PPT)   // 8192 points per block
#define BUCKETS 256
#define SEG_SHIFT 12         // log2(SPB)
#define SPB 4096             // segments per bucket; S = BUCKETS*SPB = 2^20
#define BLOCK2 1024          // stats threads/block
#define FBLOCK 256           // fallback path block size

__device__ __forceinline__ unsigned make_pay(int b, int x, int y, int z, int gs) {
    const int seg = (((b * gs + (x >> 1)) * gs + (y >> 1)) * gs) + (z >> 1);
    return ((unsigned)seg << 3) | ((unsigned)(x & 1) << 2)
         | ((unsigned)(y & 1) << 1) | (unsigned)(z & 1);
}

// ---------------- pass 1: partition points into bucket runs ----------------
__global__ __launch_bounds__(BLOCK1, 2)
void partition_kernel(const int* __restrict__ bidx,
                      const int* __restrict__ coords,
                      const int* __restrict__ gptr,
                      unsigned* __restrict__ payload,   // [BUCKETS * CAP]
                      unsigned* __restrict__ g_cursor,  // [BUCKETS]
                      int N, int CAP) {
    __shared__ uint4    s_raw4[PTS / 4];   // 32 KB raw payload cache
    __shared__ unsigned s_pay[PTS];        // 32 KB bucket-sorted payloads
    __shared__ unsigned s_h0[BUCKETS];     // histogram, wave-group 0
    __shared__ unsigned s_h1[BUCKETS];     // histogram, wave-group 1
    __shared__ unsigned s_base[BUCKETS];   // in-block exclusive offsets
    __shared__ unsigned s_old[BUCKETS];    // reserved global bases
    __shared__ unsigned s_c0[BUCKETS];     // rank cursors, group 0
    __shared__ unsigned s_c1[BUCKETS];     // rank cursors, group 1
    __shared__ unsigned s_wsum[4];         // per-wave scan totals

    const int tid = threadIdx.x;
    if (tid < BUCKETS) { s_h0[tid] = 0u; s_h1[tid] = 0u; s_c0[tid] = 0u; s_c1[tid] = 0u; }
    __syncthreads();

    const int gs = gptr[0] >> 1;           // output grid extent (64)
    const int base = blockIdx.x * PTS;
    const int cnt = min(PTS, N - base);
    const int grp = tid >> 9;              // wave-group: 0 (tid<512) / 1

    unsigned* __restrict__ myHist = grp ? s_h1 : s_h0;
    unsigned* __restrict__ myCur  = grp ? s_c1 : s_c0;

    const int4* __restrict__ bidx4 = (const int4*)bidx;
    const int4* __restrict__ crd4  = (const int4*)coords;

    // ---- phase A: single input read; pay -> LDS raw cache + split histogram.
    // Valid payloads are < 2^23, so 0xFFFFFFFF is a safe tail sentinel.
    #pragma unroll
    for (int g = 0; g < PPT / 4; ++g) {
        const int slot = g * BLOCK1 + tid;
        const int p0 = base + slot * 4;
        uint4 r;
        if (p0 + 3 < N) {
            const int q = p0 >> 2;
            const int4 b4 = bidx4[q];
            const int4 c0 = crd4[3 * q + 0];
            const int4 c1 = crd4[3 * q + 1];
            const int4 c2 = crd4[3 * q + 2];
            r.x = make_pay(b4.x, c0.x, c0.y, c0.z, gs);
            r.y = make_pay(b4.y, c0.w, c1.x, c1.y, gs);
            r.z = make_pay(b4.z, c1.z, c1.w, c2.x, gs);
            r.w = make_pay(b4.w, c2.y, c2.z, c2.w, gs);
        } else {
            unsigned t[4];
            #pragma unroll
            for (int j = 0; j < 4; ++j) {
                const int p = p0 + j;
                t[j] = (p < N)
                    ? make_pay(bidx[p], coords[3 * p + 0],
                               coords[3 * p + 1], coords[3 * p + 2], gs)
                    : 0xFFFFFFFFu;
            }
            r.x = t[0]; r.y = t[1]; r.z = t[2]; r.w = t[3];
        }
        s_raw4[slot] = r;                   // ds_write_b128
        if (r.x != 0xFFFFFFFFu) atomicAdd(&myHist[r.x >> (SEG_SHIFT + 3)], 1u);
        if (r.y != 0xFFFFFFFFu) atomicAdd(&myHist[r.y >> (SEG_SHIFT + 3)], 1u);
        if (r.z != 0xFFFFFFFFu) atomicAdd(&myHist[r.z >> (SEG_SHIFT + 3)], 1u);
        if (r.w != 0xFFFFFFFFu) atomicAdd(&myHist[r.w >> (SEG_SHIFT + 3)], 1u);
    }
    __syncthreads();

    // ---- phase B: shfl-up exclusive scan of (h0+h1) + global reservation
    unsigned v = 0u, incl = 0u;
    if (tid < BUCKETS) {
        v = s_h0[tid] + s_h1[tid];
        incl = v;
        #pragma unroll
        for (int d = 1; d < 64; d <<= 1) {
            const unsigned t = __shfl_up(incl, d, 64);
            if ((tid & 63) >= d) incl += t;
        }
        if ((tid & 63) == 63) s_wsum[tid >> 6] = incl;
    }
    __syncthreads();
    if (tid < BUCKETS) {
        const int w = tid >> 6;
        unsigned off = 0u;
        if (w > 0) off += s_wsum[0];
        if (w > 1) off += s_wsum[1];
        if (w > 2) off += s_wsum[2];
        const unsigned ex = incl - v + off;
        s_base[tid] = ex;
        s_old[tid] = atomicAdd(&g_cursor[tid], v);   // 256 atomics/block
    }
    __syncthreads();

    // ---- phase C: re-rank from LDS raw cache with SPLIT cursors.
    // Group 0 places at s_base[bk]+r0; group 1 at s_base[bk]+h0[bk]+r1.
    // Ranks are unique; s_pay[0..cnt) fully covered.
    #pragma unroll
    for (int g = 0; g < PPT / 4; ++g) {
        const uint4 r = s_raw4[g * BLOCK1 + tid];    // ds_read_b128
        unsigned bk, rk;
        if (r.x != 0xFFFFFFFFu) {
            bk = r.x >> (SEG_SHIFT + 3);
            rk = atomicAdd(&myCur[bk], 1u) + (grp ? s_h0[bk] : 0u);
            s_pay[s_base[bk] + rk] = r.x;
        }
        if (r.y != 0xFFFFFFFFu) {
            bk = r.y >> (SEG_SHIFT + 3);
            rk = atomicAdd(&myCur[bk], 1u) + (grp ? s_h0[bk] : 0u);
            s_pay[s_base[bk] + rk] = r.y;
        }
        if (r.z != 0xFFFFFFFFu) {
            bk = r.z >> (SEG_SHIFT + 3);
            rk = atomicAdd(&myCur[bk], 1u) + (grp ? s_h0[bk] : 0u);
            s_pay[s_base[bk] + rk] = r.z;
        }
        if (r.w != 0xFFFFFFFFu) {
            bk = r.w >> (SEG_SHIFT + 3);
            rk = atomicAdd(&myCur[bk], 1u) + (grp ? s_h0[bk] : 0u);
            s_pay[s_base[bk] + rk] = r.w;
        }
    }
    __syncthreads();

    // ---- phase D: coalesced copy-out; uint4 LDS reads, scalar stores
    const uint4* __restrict__ s_pay4 = (const uint4*)s_pay;
    const int nq = cnt >> 2;
    for (int j4 = tid; j4 < nq; j4 += BLOCK1) {
        const uint4 p = s_pay4[j4];                  // ds_read_b128
        const int j = j4 * 4;
        unsigned bk, off;
        bk = p.x >> (SEG_SHIFT + 3);
        off = s_old[bk] + ((unsigned)(j + 0) - s_base[bk]);
        if (off < (unsigned)CAP) payload[(size_t)bk * CAP + off] = p.x;
        bk = p.y >> (SEG_SHIFT + 3);
        off = s_old[bk] + ((unsigned)(j + 1) - s_base[bk]);
        if (off < (unsigned)CAP) payload[(size_t)bk * CAP + off] = p.y;
        bk = p.z >> (SEG_SHIFT + 3);
        off = s_old[bk] + ((unsigned)(j + 2) - s_base[bk]);
        if (off < (unsigned)CAP) payload[(size_t)bk * CAP + off] = p.z;
        bk = p.w >> (SEG_SHIFT + 3);
        off = s_old[bk] + ((unsigned)(j + 3) - s_base[bk]);
        if (off < (unsigned)CAP) payload[(size_t)bk * CAP + off] = p.w;
    }
    for (int j = (nq << 2) + tid; j < cnt; j += BLOCK1) {
        const unsigned p = s_pay[j];
        const unsigned bk = p >> (SEG_SHIFT + 3);
        const unsigned off = s_old[bk] + ((unsigned)j - s_base[bk]);
        if (off < (unsigned)CAP) payload[(size_t)bk * CAP + off] = p;
    }
}

// -------- pass 2: per-bucket LDS accumulation + fused finalize --------
__global__ __launch_bounds__(BLOCK2)
void stats_kernel(const unsigned* __restrict__ payload,
                  const unsigned* __restrict__ g_cursor,
                  float* __restrict__ out, int CAP) {
    __shared__ unsigned fine[SPB];        // 16 KB packed (count,ux,uy,uz)
    __shared__ float s_stage[BLOCK2 * 7]; // 28 KB row staging for coalesced out
    __shared__ float s_ginv;

    const int tid = threadIdx.x;
    const int k = blockIdx.x;

    for (int s = tid; s < SPB; s += BLOCK2) fine[s] = 0u;
    if (tid < 64) {                       // single-wave shfl reduction of glob
        unsigned g = g_cursor[(k & ~63) + tid];   // 64 buckets/batch
        #pragma unroll
        for (int o = 32; o > 0; o >>= 1) g += __shfl_down(g, o, 64);
        if (tid == 0) s_ginv = 1.0f / (float)g;   // unused if batch empty
    }
    __syncthreads();
    const float ginv = s_ginv;

    unsigned cnt = g_cursor[k];
    if (cnt > (unsigned)CAP) cnt = (unsigned)CAP;
    const uint4* __restrict__ pay4 = (const uint4*)(payload + (size_t)k * CAP);
    const unsigned n4 = cnt >> 2;

    for (unsigned j = tid; j < n4; j += BLOCK2) {
        const uint4 p = pay4[j];
        atomicAdd(&fine[(p.x >> 3) & (SPB - 1)],
                  (1u << 24) | ((p.x & 4u) << 14) | ((p.x & 2u) << 7) | (p.x & 1u));
        atomicAdd(&fine[(p.y >> 3) & (SPB - 1)],
                  (1u << 24) | ((p.y & 4u) << 14) | ((p.y & 2u) << 7) | (p.y & 1u));
        atomicAdd(&fine[(p.z >> 3) & (SPB - 1)],
                  (1u << 24) | ((p.z & 4u) << 14) | ((p.z & 2u) << 7) | (p.z & 1u));
        atomicAdd(&fine[(p.w >> 3) & (SPB - 1)],
                  (1u << 24) | ((p.w & 4u) << 14) | ((p.w & 2u) << 7) | (p.w & 1u));
    }
    for (unsigned j = (n4 << 2) + tid; j < cnt; j += BLOCK2) {
        const unsigned p = payload[(size_t)k * CAP + j];
        atomicAdd(&fine[(p >> 3) & (SPB - 1)],
                  (1u << 24) | ((p & 4u) << 14) | ((p & 2u) << 7) | (p & 1u));
    }
    __syncthreads();

    // finalize in 4 tiles of 1024 rows: compute -> LDS stage -> float4 out
    for (int t = 0; t < SPB; t += BLOCK2) {
        const unsigned a = fine[t + tid];
        const int c = (int)(a >> 24);
        float d0 = 0.f, vx = 0.f, vy = 0.f, vz = 0.f, mx = 0.f, my = 0.f, mz = 0.f;
        if (c > 0) {
            const float inv = 1.0f / (float)c;
            mx = (float)((a >> 16) & 0xffu) * inv;
            my = (float)((a >> 8) & 0xffu) * inv;
            mz = (float)(a & 0xffu) * inv;
            vx = mx - mx * mx;
            vy = my - my * my;
            vz = mz - mz * mz;
            d0 = (float)c * ginv;
        }
        float* st = &s_stage[tid * 7];
        st[0] = d0;
        st[1] = vx; st[2] = vy; st[3] = vz;
        st[4] = mx; st[5] = my; st[6] = mz;
        __syncthreads();

        const float4* src = (const float4*)s_stage;
        float4* dst = (float4*)(out + ((size_t)k * SPB + t) * 7);
        #pragma unroll
        for (int j = 0; j < 2; ++j) {
            const int idx = j * BLOCK2 + tid;
            if (idx < (BLOCK2 * 7) / 4) dst[idx] = src[idx];
        }
        __syncthreads();
    }
}

// ---------------- fallback (round-2 path, known-good) ----------------
__global__ __launch_bounds__(FBLOCK)
void accum_kernel(const int* __restrict__ bidx,
                  const int* __restrict__ coords,
                  const int* __restrict__ gptr,
                  unsigned* __restrict__ acc, int astride,
                  int* __restrict__ glob, int N) {
    __shared__ int gcnt[4];
    if (threadIdx.x < 4) gcnt[threadIdx.x] = 0;
    __syncthreads();
    const int gs = gptr[0] >> 1;
    int l0 = 0, l1 = 0, l2 = 0, l3 = 0;
    const int stride = gridDim.x * blockDim.x;
    for (int i = blockIdx.x * blockDim.x + threadIdx.x; i < N; i += stride) {
        const int b  = bidx[i];
        const int cx = coords[3 * i + 0];
        const int cy = coords[3 * i + 1];
        const int cz = coords[3 * i + 2];
        const int seg = (((b * gs + (cx >> 1)) * gs + (cy >> 1)) * gs) + (cz >> 1);
        const unsigned val = (1u << 24)
                           | ((unsigned)(cx & 1) << 16)
                           | ((unsigned)(cy & 1) << 8)
                           |  (unsigned)(cz & 1);
        atomicAdd(&acc[(size_t)seg * astride], val);
        l0 += (b == 0); l1 += (b == 1); l2 += (b == 2); l3 += (b == 3);
    }
    if (l0) atomicAdd(&gcnt[0], l0);
    if (l1) atomicAdd(&gcnt[1], l1);
    if (l2) atomicAdd(&gcnt[2], l2);
    if (l3) atomicAdd(&gcnt[3], l3);
    __syncthreads();
    if (threadIdx.x < 4 && gcnt[threadIdx.x] != 0)
        atomicAdd(&glob[threadIdx.x], gcnt[threadIdx.x]);
}

__global__ __launch_bounds__(FBLOCK)
void finalize_kernel(const unsigned* __restrict__ acc, int astride,
                     const int* __restrict__ glob,
                     float* __restrict__ out, int S, int pbShift) {
    const int s = blockIdx.x * blockDim.x + threadIdx.x;
    if (s >= S) return;
    const unsigned a = acc[(size_t)s * astride];
    const int b = s >> pbShift;
    const int c = (int)(a >> 24);
    float d0 = 0.f, vx = 0.f, vy = 0.f, vz = 0.f, mx = 0.f, my = 0.f, mz = 0.f;
    if (c > 0) {
        const float inv = 1.0f / (float)c;
        mx = (float)((a >> 16) & 0xffu) * inv;
        my = (float)((a >> 8) & 0xffu) * inv;
        mz = (float)(a & 0xffu) * inv;
        vx = mx - mx * mx; vy = my - my * my; vz = mz - mz * mz;
        d0 = (float)c / (float)glob[b];
    }
    float* row = out + (size_t)s * 7;
    row[0] = d0;
    row[1] = vx; row[2] = vy; row[3] = vz;
    row[4] = mx; row[5] = my; row[6] = mz;
}

extern "C" void kernel_launch(void* const* d_in, const int* in_sizes, int n_in,
                              void* d_out, int out_size, void* d_ws, size_t ws_size,
                              hipStream_t stream) {
    const int* bidx   = (const int*)d_in[1];   // batch_idx [N]
    const int* coords = (const int*)d_in[2];   // coords [N,3]
    const int* gptr   = (const int*)d_in[3];   // grid_size scalar (128)

    const int N = in_sizes[1];
    const int S = out_size / 7;                // 1,048,576
    const int per_batch = S / 4;               // B = 4

    const int NpB = (N + BUCKETS - 1) / BUCKETS;
    const int CAP = ((NpB + NpB / 8 + 64) + 63) & ~63;   // ~+15 sigma headroom
    const size_t need = 1024 + (size_t)BUCKETS * (size_t)CAP * 4u;

    const bool fast = (S == (BUCKETS * SPB)) && (per_batch / SPB == 64) &&
                      (ws_size >= need) && (N > 0);

    if (fast) {
        unsigned* g_cursor = (unsigned*)d_ws;                 // 1 KB
        unsigned* payload  = (unsigned*)((char*)d_ws + 1024); // 256*CAP u32
        hipMemsetAsync(d_ws, 0, 1024, stream);

        const int blocks = (N + PTS - 1) / PTS;               // 489
        partition_kernel<<<blocks, BLOCK1, 0, stream>>>(
            bidx, coords, gptr, payload, g_cursor, N, CAP);
        stats_kernel<<<BUCKETS, BLOCK2, 0, stream>>>(
            payload, g_cursor, (float*)d_out, CAP);
    } else {
        // known-good round-2 path
        int pbShift = 0;
        while ((1 << pbShift) < per_batch) ++pbShift;
        int* glob = (int*)d_ws;
        const size_t accBytes = (size_t)S * sizeof(unsigned);
        unsigned* acc;
        int astride;
        if (ws_size >= accBytes + 64) {
            acc = (unsigned*)((char*)d_ws + 64);
            astride = 1;
            hipMemsetAsync(d_ws, 0, 64 + accBytes, stream);
        } else {
            acc = (unsigned*)d_out;
            astride = 7;
            hipMemsetAsync(d_out, 0, (size_t)out_size * sizeof(float), stream);
            hipMemsetAsync(d_ws, 0, 64, stream);
        }
        int accBlocks = (N + FBLOCK - 1) / FBLOCK;
        if (accBlocks > 2048) accBlocks = 2048;
        accum_kernel<<<accBlocks, FBLOCK, 0, stream>>>(bidx, coords, gptr,
                                                       acc, astride, glob, N);
        const int finBlocks = (S + FBLOCK - 1) / FBLOCK;
        finalize_kernel<<<finBlocks, FBLOCK, 0, stream>>>(acc, astride, glob,
                                                          (float*)d_out, S, pbShift);
    }
}